// Round 1
// baseline (191.329 us; speedup 1.0000x reference)
//
#include <hip/hip_runtime.h>
#include <math.h>

#define LL 512
#define EE 5120
#define RR 160
#define NS 16
#define NTOT 192   // 160 + 16 + 16
#define KS 8
#define KCHUNK 640 // 5120/8

__device__ inline float softplus_t(float z) {
    // matches: where(z > 20, z, log1p(exp(min(z, 20))))
    return z > 20.f ? z : log1pf(__expf(fminf(z, 20.f)));
}

// G1: partial fused GEMM: part[ks][L][192] = x[:, kchunk] @ [Wlow | WB | WC][kchunk, :]
__global__ void g1_kernel(const float* __restrict__ x,
                          const float* __restrict__ Wlow,
                          const float* __restrict__ WB,
                          const float* __restrict__ WC,
                          float* __restrict__ part) {
    __shared__ __align__(16) float xs[16][33];   // [k][m], padded
    __shared__ __align__(16) float wsh[16][64];  // [k][n]
    const int m0 = blockIdx.x * 32;
    const int n0 = blockIdx.y * 64;
    const int ks = blockIdx.z;
    const int tid = threadIdx.x;
    const int tx = tid & 15, ty = tid >> 4;
    float4 acc0 = {0,0,0,0}, acc1 = {0,0,0,0};
    const int kbase = ks * KCHUNK;
    const int sj = tid >> 4;         // staging row (k) 0..15
    const int sc = (tid & 15) * 4;   // staging col 0..60
    const int gc = n0 + sc;          // global col 0..188

    for (int ko = 0; ko < KCHUNK / 16; ++ko) {
        const int kc = kbase + ko * 16;
        // stage x tile (32 m x 16 k), transposed into xs[k][m]
        {
            int v0 = tid, v1 = tid + 256;
            int k0 = v0 & 15, mm0 = v0 >> 4;
            int k1 = v1 & 15, mm1 = v1 >> 4;
            xs[k0][mm0] = x[(size_t)(m0 + mm0) * EE + kc + k0];
            xs[k1][mm1] = x[(size_t)(m0 + mm1) * EE + kc + k1];
        }
        // stage W tile (16 k x 64 n) from the appropriate source array
        {
            float4 wv;
            int krow = kc + sj;
            if (gc < RR) {
                wv = *reinterpret_cast<const float4*>(&Wlow[(size_t)krow * RR + gc]);
            } else if (gc < RR + NS) {
                wv = *reinterpret_cast<const float4*>(&WB[(size_t)krow * NS + (gc - RR)]);
            } else {
                wv = *reinterpret_cast<const float4*>(&WC[(size_t)krow * NS + (gc - RR - NS)]);
            }
            *reinterpret_cast<float4*>(&wsh[sj][sc]) = wv;
        }
        __syncthreads();
#pragma unroll
        for (int k = 0; k < 16; ++k) {
            float a0 = xs[k][ty];
            float a1 = xs[k][ty + 16];
            float4 b = *reinterpret_cast<const float4*>(&wsh[k][tx * 4]);
            acc0.x += a0 * b.x; acc0.y += a0 * b.y; acc0.z += a0 * b.z; acc0.w += a0 * b.w;
            acc1.x += a1 * b.x; acc1.y += a1 * b.y; acc1.z += a1 * b.z; acc1.w += a1 * b.w;
        }
        __syncthreads();
    }
    {
        int m_a = m0 + ty;
        int m_b = m0 + ty + 16;
        size_t basea = ((size_t)ks * LL + m_a) * NTOT + n0 + tx * 4;
        size_t baseb = ((size_t)ks * LL + m_b) * NTOT + n0 + tx * 4;
        *reinterpret_cast<float4*>(&part[basea]) = acc0;
        *reinterpret_cast<float4*>(&part[baseb]) = acc1;
    }
}

// R1: reduce split-K partials into tmp [512][160], Bb [512][16], Cb [512][16]
__global__ void r1_kernel(const float* __restrict__ part,
                          float* __restrict__ tmp,
                          float* __restrict__ Bb,
                          float* __restrict__ Cb) {
    int idx = blockIdx.x * 256 + threadIdx.x; // 0..98303
    int m = idx / NTOT, j = idx % NTOT;
    float s = 0.f;
#pragma unroll
    for (int ks = 0; ks < KS; ++ks) s += part[(size_t)ks * LL * NTOT + idx];
    if (j < RR) tmp[m * RR + j] = s;
    else if (j < RR + NS) Bb[m * NS + (j - RR)] = s;
    else Cb[m * NS + (j - RR - NS)] = s;
}

// G2: delta = softplus(tmp @ W_dt + bias) -> written into d_out (reused as delta storage)
__global__ void g2_kernel(const float* __restrict__ tmp,
                          const float* __restrict__ Wdt,
                          const float* __restrict__ bias,
                          float* __restrict__ delta) {
    __shared__ __align__(16) float ts[16][33];
    __shared__ __align__(16) float wsh[16][64];
    const int m0 = blockIdx.x * 32;
    const int n0 = blockIdx.y * 64;
    const int tid = threadIdx.x;
    const int tx = tid & 15, ty = tid >> 4;
    float4 acc0 = {0,0,0,0}, acc1 = {0,0,0,0};
    const int sj = tid >> 4;
    const int sc = (tid & 15) * 4;

    for (int ko = 0; ko < RR / 16; ++ko) {
        const int kc = ko * 16;
        {
            int v0 = tid, v1 = tid + 256;
            int k0 = v0 & 15, mm0 = v0 >> 4;
            int k1 = v1 & 15, mm1 = v1 >> 4;
            ts[k0][mm0] = tmp[(m0 + mm0) * RR + kc + k0];
            ts[k1][mm1] = tmp[(m0 + mm1) * RR + kc + k1];
        }
        *reinterpret_cast<float4*>(&wsh[sj][sc]) =
            *reinterpret_cast<const float4*>(&Wdt[(size_t)(kc + sj) * EE + n0 + sc]);
        __syncthreads();
#pragma unroll
        for (int k = 0; k < 16; ++k) {
            float a0 = ts[k][ty];
            float a1 = ts[k][ty + 16];
            float4 b = *reinterpret_cast<const float4*>(&wsh[k][tx * 4]);
            acc0.x += a0 * b.x; acc0.y += a0 * b.y; acc0.z += a0 * b.z; acc0.w += a0 * b.w;
            acc1.x += a1 * b.x; acc1.y += a1 * b.y; acc1.z += a1 * b.z; acc1.w += a1 * b.w;
        }
        __syncthreads();
    }
    float4 bv = *reinterpret_cast<const float4*>(&bias[n0 + tx * 4]);
    float4 o0, o1;
    o0.x = softplus_t(acc0.x + bv.x); o0.y = softplus_t(acc0.y + bv.y);
    o0.z = softplus_t(acc0.z + bv.z); o0.w = softplus_t(acc0.w + bv.w);
    o1.x = softplus_t(acc1.x + bv.x); o1.y = softplus_t(acc1.y + bv.y);
    o1.z = softplus_t(acc1.z + bv.z); o1.w = softplus_t(acc1.w + bv.w);
    int m_a = m0 + ty, m_b = m0 + ty + 16;
    *reinterpret_cast<float4*>(&delta[(size_t)m_a * EE + n0 + tx * 4]) = o0;
    *reinterpret_cast<float4*>(&delta[(size_t)m_b * EE + n0 + tx * 4]) = o1;
}

// S: fused scan + y reduction + skip connection. delta lives in `out`, overwritten in place.
__global__ void scan_kernel(const float* __restrict__ x,
                            const float* __restrict__ Bb,
                            const float* __restrict__ Cb,
                            const float* __restrict__ A_log,
                            const float* __restrict__ Dvec,
                            float* __restrict__ out) {
    __shared__ float d_lds[32][16];
    __shared__ float x_lds[32][16];
    __shared__ float b_lds[32][16];
    __shared__ float c_lds[32][16];
    __shared__ float y_lds[32][16];
    __shared__ float D_s[16];
    const int tid = threadIdx.x;
    const int e0 = blockIdx.x * 16;
    const int el = tid >> 4;  // 0..15 local e
    const int n  = tid & 15;  // 0..15 state index
    if (tid < 16) D_s[tid] = Dvec[e0 + tid];
    const float Acoef = -__expf(A_log[(size_t)(e0 + el) * NS + n]);
    float h = 0.f;

    for (int t0 = 0; t0 < LL; t0 += 32) {
        for (int v = tid; v < 512; v += 256) {
            int t = v >> 4, e = v & 15;
            d_lds[t][e] = out[(size_t)(t0 + t) * EE + e0 + e]; // delta
            x_lds[t][e] = x[(size_t)(t0 + t) * EE + e0 + e];
            b_lds[t][e] = Bb[(t0 + t) * NS + e];
            c_lds[t][e] = Cb[(t0 + t) * NS + e];
        }
        __syncthreads();
        for (int tt = 0; tt < 32; ++tt) {
            float d  = d_lds[tt][el];
            float xv = x_lds[tt][el];
            float Bv = b_lds[tt][n];
            float Cv = c_lds[tt][n];
            float a = __expf(d * Acoef);
            h = a * h + d * Bv * xv;
            float p = h * Cv;
            p += __shfl_xor(p, 1);
            p += __shfl_xor(p, 2);
            p += __shfl_xor(p, 4);
            p += __shfl_xor(p, 8);
            if (n == 0) y_lds[tt][el] = p;
        }
        __syncthreads();
        for (int v = tid; v < 512; v += 256) {
            int t = v >> 4, e = v & 15;
            out[(size_t)(t0 + t) * EE + e0 + e] = x_lds[t][e] * D_s[e] + y_lds[t][e];
        }
        __syncthreads();
    }
}

extern "C" void kernel_launch(void* const* d_in, const int* in_sizes, int n_in,
                              void* d_out, int out_size, void* d_ws, size_t ws_size,
                              hipStream_t stream) {
    const float* x     = (const float*)d_in[0];
    const float* Wlow  = (const float*)d_in[1];
    const float* Wdt   = (const float*)d_in[2];
    const float* bias  = (const float*)d_in[3];
    const float* WB    = (const float*)d_in[4];
    const float* WC    = (const float*)d_in[5];
    const float* Alog  = (const float*)d_in[6];
    const float* Dv    = (const float*)d_in[7];
    float* out = (float*)d_out;
    float* wsf = (float*)d_ws;

    float* part = wsf;                                // [8][512][192]
    float* tmp  = wsf + (size_t)KS * LL * NTOT;       // [512][160]
    float* Bb   = tmp + (size_t)LL * RR;              // [512][16]
    float* Cb   = Bb + (size_t)LL * NS;               // [512][16]

    g1_kernel<<<dim3(16, 3, 8), 256, 0, stream>>>(x, Wlow, WB, WC, part);
    r1_kernel<<<dim3(384), 256, 0, stream>>>(part, tmp, Bb, Cb);
    g2_kernel<<<dim3(16, 80), 256, 0, stream>>>(tmp, Wdt, bias, out);
    scan_kernel<<<dim3(320), 256, 0, stream>>>(x, Bb, Cb, Alog, Dv, out);
}

// Round 2
// 125.347 us; speedup vs baseline: 1.5264x; 1.5264x over previous
//
#include <hip/hip_runtime.h>
#include <math.h>

#define LL 512
#define EE 5120
#define RR 160
#define NS 16
#define NTOT 192   // 160 + 16 + 16
#define KS 8
#define KCHUNK 640 // 5120/8
#define CH 32      // timesteps per chunk
#define NC 16      // number of chunks (LL/CH)

__device__ inline float softplus_t(float z) {
    // matches: where(z > 20, z, log1p(exp(min(z, 20))))
    return z > 20.f ? z : log1pf(__expf(fminf(z, 20.f)));
}

// G1: partial fused GEMM: part[ks][L][192] = x[:, kchunk] @ [Wlow | WB | WC][kchunk, :]
__global__ void g1_kernel(const float* __restrict__ x,
                          const float* __restrict__ Wlow,
                          const float* __restrict__ WB,
                          const float* __restrict__ WC,
                          float* __restrict__ part) {
    __shared__ __align__(16) float xs[16][33];   // [k][m], padded
    __shared__ __align__(16) float wsh[16][64];  // [k][n]
    const int m0 = blockIdx.x * 32;
    const int n0 = blockIdx.y * 64;
    const int ks = blockIdx.z;
    const int tid = threadIdx.x;
    const int tx = tid & 15, ty = tid >> 4;
    float4 acc0 = {0,0,0,0}, acc1 = {0,0,0,0};
    const int kbase = ks * KCHUNK;
    const int sj = tid >> 4;         // staging row (k) 0..15
    const int sc = (tid & 15) * 4;   // staging col 0..60
    const int gc = n0 + sc;          // global col 0..188

    for (int ko = 0; ko < KCHUNK / 16; ++ko) {
        const int kc = kbase + ko * 16;
        {
            int v0 = tid, v1 = tid + 256;
            int k0 = v0 & 15, mm0 = v0 >> 4;
            int k1 = v1 & 15, mm1 = v1 >> 4;
            xs[k0][mm0] = x[(size_t)(m0 + mm0) * EE + kc + k0];
            xs[k1][mm1] = x[(size_t)(m0 + mm1) * EE + kc + k1];
        }
        {
            float4 wv;
            int krow = kc + sj;
            if (gc < RR) {
                wv = *reinterpret_cast<const float4*>(&Wlow[(size_t)krow * RR + gc]);
            } else if (gc < RR + NS) {
                wv = *reinterpret_cast<const float4*>(&WB[(size_t)krow * NS + (gc - RR)]);
            } else {
                wv = *reinterpret_cast<const float4*>(&WC[(size_t)krow * NS + (gc - RR - NS)]);
            }
            *reinterpret_cast<float4*>(&wsh[sj][sc]) = wv;
        }
        __syncthreads();
#pragma unroll
        for (int k = 0; k < 16; ++k) {
            float a0 = xs[k][ty];
            float a1 = xs[k][ty + 16];
            float4 b = *reinterpret_cast<const float4*>(&wsh[k][tx * 4]);
            acc0.x += a0 * b.x; acc0.y += a0 * b.y; acc0.z += a0 * b.z; acc0.w += a0 * b.w;
            acc1.x += a1 * b.x; acc1.y += a1 * b.y; acc1.z += a1 * b.z; acc1.w += a1 * b.w;
        }
        __syncthreads();
    }
    {
        int m_a = m0 + ty;
        int m_b = m0 + ty + 16;
        size_t basea = ((size_t)ks * LL + m_a) * NTOT + n0 + tx * 4;
        size_t baseb = ((size_t)ks * LL + m_b) * NTOT + n0 + tx * 4;
        *reinterpret_cast<float4*>(&part[basea]) = acc0;
        *reinterpret_cast<float4*>(&part[baseb]) = acc1;
    }
}

// R1: reduce split-K partials into tmp [512][160], Bb [512][16], Cb [512][16]
__global__ void r1_kernel(const float* __restrict__ part,
                          float* __restrict__ tmp,
                          float* __restrict__ Bb,
                          float* __restrict__ Cb) {
    int idx = blockIdx.x * 256 + threadIdx.x; // 0..98303
    int m = idx / NTOT, j = idx % NTOT;
    float s = 0.f;
#pragma unroll
    for (int ks = 0; ks < KS; ++ks) s += part[(size_t)ks * LL * NTOT + idx];
    if (j < RR) tmp[m * RR + j] = s;
    else if (j < RR + NS) Bb[m * NS + (j - RR)] = s;
    else Cb[m * NS + (j - RR - NS)] = s;
}

// G2: delta = softplus(tmp @ W_dt + bias) -> written into d_out (reused as delta storage)
__global__ void g2_kernel(const float* __restrict__ tmp,
                          const float* __restrict__ Wdt,
                          const float* __restrict__ bias,
                          float* __restrict__ delta) {
    __shared__ __align__(16) float ts[16][33];
    __shared__ __align__(16) float wsh[16][64];
    const int m0 = blockIdx.x * 32;
    const int n0 = blockIdx.y * 64;
    const int tid = threadIdx.x;
    const int tx = tid & 15, ty = tid >> 4;
    float4 acc0 = {0,0,0,0}, acc1 = {0,0,0,0};
    const int sj = tid >> 4;
    const int sc = (tid & 15) * 4;

    for (int ko = 0; ko < RR / 16; ++ko) {
        const int kc = ko * 16;
        {
            int v0 = tid, v1 = tid + 256;
            int k0 = v0 & 15, mm0 = v0 >> 4;
            int k1 = v1 & 15, mm1 = v1 >> 4;
            ts[k0][mm0] = tmp[(m0 + mm0) * RR + kc + k0];
            ts[k1][mm1] = tmp[(m0 + mm1) * RR + kc + k1];
        }
        *reinterpret_cast<float4*>(&wsh[sj][sc]) =
            *reinterpret_cast<const float4*>(&Wdt[(size_t)(kc + sj) * EE + n0 + sc]);
        __syncthreads();
#pragma unroll
        for (int k = 0; k < 16; ++k) {
            float a0 = ts[k][ty];
            float a1 = ts[k][ty + 16];
            float4 b = *reinterpret_cast<const float4*>(&wsh[k][tx * 4]);
            acc0.x += a0 * b.x; acc0.y += a0 * b.y; acc0.z += a0 * b.z; acc0.w += a0 * b.w;
            acc1.x += a1 * b.x; acc1.y += a1 * b.y; acc1.z += a1 * b.z; acc1.w += a1 * b.w;
        }
        __syncthreads();
    }
    float4 bv = *reinterpret_cast<const float4*>(&bias[n0 + tx * 4]);
    float4 o0, o1;
    o0.x = softplus_t(acc0.x + bv.x); o0.y = softplus_t(acc0.y + bv.y);
    o0.z = softplus_t(acc0.z + bv.z); o0.w = softplus_t(acc0.w + bv.w);
    o1.x = softplus_t(acc1.x + bv.x); o1.y = softplus_t(acc1.y + bv.y);
    o1.z = softplus_t(acc1.z + bv.z); o1.w = softplus_t(acc1.w + bv.w);
    int m_a = m0 + ty, m_b = m0 + ty + 16;
    *reinterpret_cast<float4*>(&delta[(size_t)m_a * EE + n0 + tx * 4]) = o0;
    *reinterpret_cast<float4*>(&delta[(size_t)m_b * EE + n0 + tx * 4]) = o1;
}

// ---- chunked scan: Pass A — per-chunk local scan, thread per e, 16 n's in registers
__global__ __launch_bounds__(256) void passA_kernel(
        const float* __restrict__ delta,  // lives in d_out
        const float* __restrict__ x,
        const float* __restrict__ Bb,
        const float* __restrict__ A_log,
        float* __restrict__ Pc,
        float* __restrict__ Hloc) {
    __shared__ float b_lds[CH][NS];
    const int c = blockIdx.y;
    const int e = blockIdx.x * 256 + threadIdx.x;
    const int t0 = c * CH;
    for (int v = threadIdx.x; v < CH * NS; v += 256)
        b_lds[v >> 4][v & 15] = Bb[t0 * NS + v];
    __syncthreads();

    float Ac[NS];
#pragma unroll
    for (int q = 0; q < 4; ++q) {
        float4 al = *reinterpret_cast<const float4*>(&A_log[(size_t)e * NS + q * 4]);
        Ac[q * 4 + 0] = -__expf(al.x);
        Ac[q * 4 + 1] = -__expf(al.y);
        Ac[q * 4 + 2] = -__expf(al.z);
        Ac[q * 4 + 3] = -__expf(al.w);
    }
    float h[NS];
#pragma unroll
    for (int n = 0; n < NS; ++n) h[n] = 0.f;
    float sumd = 0.f;

#pragma unroll 4
    for (int tt = 0; tt < CH; ++tt) {
        float d  = delta[(size_t)(t0 + tt) * EE + e];
        float xv = x[(size_t)(t0 + tt) * EE + e];
        sumd += d;
        float bx = d * xv;
#pragma unroll
        for (int n = 0; n < NS; ++n) {
            float a = __expf(d * Ac[n]);
            h[n] = a * h[n] + bx * b_lds[tt][n];
        }
    }
    size_t base = ((size_t)c * EE + e) * NS;
#pragma unroll
    for (int q = 0; q < 4; ++q) {
        float4 hv = {h[q*4], h[q*4+1], h[q*4+2], h[q*4+3]};
        *reinterpret_cast<float4*>(&Hloc[base + q * 4]) = hv;
        float4 pv;
        pv.x = __expf(Ac[q*4+0] * sumd);
        pv.y = __expf(Ac[q*4+1] * sumd);
        pv.z = __expf(Ac[q*4+2] * sumd);
        pv.w = __expf(Ac[q*4+3] * sumd);
        *reinterpret_cast<float4*>(&Pc[base + q * 4]) = pv;
    }
}

// Pass B — sequential combine over chunks (trivial), emits per-chunk starting state
__global__ __launch_bounds__(256) void passB_kernel(
        const float* __restrict__ Pc,
        const float* __restrict__ Hloc,
        float* __restrict__ Hstart) {
    const size_t idx = (size_t)blockIdx.x * 256 + threadIdx.x; // (e,n) flat, 81920
    float h = 0.f;
#pragma unroll
    for (int c = 0; c < NC; ++c) {
        size_t off = (size_t)c * EE * NS + idx;
        Hstart[off] = h;
        h = Pc[off] * h + Hloc[off];
    }
}

// Pass C — re-run chunk scans seeded with Hstart, in-register y reduction, fused skip
__global__ __launch_bounds__(256) void passC_kernel(
        const float* __restrict__ x,
        const float* __restrict__ Bb,
        const float* __restrict__ Cb,
        const float* __restrict__ A_log,
        const float* __restrict__ Dvec,
        const float* __restrict__ Hstart,
        float* __restrict__ out) {   // holds delta on entry, final output on exit
    __shared__ float b_lds[CH][NS];
    __shared__ float c_lds[CH][NS];
    const int c = blockIdx.y;
    const int e = blockIdx.x * 256 + threadIdx.x;
    const int t0 = c * CH;
    for (int v = threadIdx.x; v < CH * NS; v += 256) {
        b_lds[v >> 4][v & 15] = Bb[t0 * NS + v];
        c_lds[v >> 4][v & 15] = Cb[t0 * NS + v];
    }
    __syncthreads();

    float Ac[NS];
#pragma unroll
    for (int q = 0; q < 4; ++q) {
        float4 al = *reinterpret_cast<const float4*>(&A_log[(size_t)e * NS + q * 4]);
        Ac[q * 4 + 0] = -__expf(al.x);
        Ac[q * 4 + 1] = -__expf(al.y);
        Ac[q * 4 + 2] = -__expf(al.z);
        Ac[q * 4 + 3] = -__expf(al.w);
    }
    float h[NS];
    size_t hbase = ((size_t)c * EE + e) * NS;
#pragma unroll
    for (int q = 0; q < 4; ++q) {
        float4 hv = *reinterpret_cast<const float4*>(&Hstart[hbase + q * 4]);
        h[q*4+0] = hv.x; h[q*4+1] = hv.y; h[q*4+2] = hv.z; h[q*4+3] = hv.w;
    }
    const float Dval = Dvec[e];

#pragma unroll 4
    for (int tt = 0; tt < CH; ++tt) {
        float d  = out[(size_t)(t0 + tt) * EE + e];   // delta
        float xv = x[(size_t)(t0 + tt) * EE + e];
        float bx = d * xv;
        float y = 0.f;
#pragma unroll
        for (int n = 0; n < NS; ++n) {
            float a = __expf(d * Ac[n]);
            h[n] = a * h[n] + bx * b_lds[tt][n];
            y += h[n] * c_lds[tt][n];
        }
        out[(size_t)(t0 + tt) * EE + e] = xv * Dval + y;
    }
}

// Fallback sequential scan (used only if workspace is too small for carries)
__global__ void scan_kernel(const float* __restrict__ x,
                            const float* __restrict__ Bb,
                            const float* __restrict__ Cb,
                            const float* __restrict__ A_log,
                            const float* __restrict__ Dvec,
                            float* __restrict__ out) {
    __shared__ float d_lds[32][16];
    __shared__ float x_lds[32][16];
    __shared__ float b_lds[32][16];
    __shared__ float c_lds[32][16];
    __shared__ float y_lds[32][16];
    __shared__ float D_s[16];
    const int tid = threadIdx.x;
    const int e0 = blockIdx.x * 16;
    const int el = tid >> 4;
    const int n  = tid & 15;
    if (tid < 16) D_s[tid] = Dvec[e0 + tid];
    const float Acoef = -__expf(A_log[(size_t)(e0 + el) * NS + n]);
    float h = 0.f;
    for (int t0 = 0; t0 < LL; t0 += 32) {
        for (int v = tid; v < 512; v += 256) {
            int t = v >> 4, e = v & 15;
            d_lds[t][e] = out[(size_t)(t0 + t) * EE + e0 + e];
            x_lds[t][e] = x[(size_t)(t0 + t) * EE + e0 + e];
            b_lds[t][e] = Bb[(t0 + t) * NS + e];
            c_lds[t][e] = Cb[(t0 + t) * NS + e];
        }
        __syncthreads();
        for (int tt = 0; tt < 32; ++tt) {
            float d  = d_lds[tt][el];
            float xv = x_lds[tt][el];
            float a = __expf(d * Acoef);
            h = a * h + d * b_lds[tt][n] * xv;
            float p = h * c_lds[tt][n];
            p += __shfl_xor(p, 1);
            p += __shfl_xor(p, 2);
            p += __shfl_xor(p, 4);
            p += __shfl_xor(p, 8);
            if (n == 0) y_lds[tt][el] = p;
        }
        __syncthreads();
        for (int v = tid; v < 512; v += 256) {
            int t = v >> 4, e = v & 15;
            out[(size_t)(t0 + t) * EE + e0 + e] = x_lds[t][e] * D_s[e] + y_lds[t][e];
        }
        __syncthreads();
    }
}

extern "C" void kernel_launch(void* const* d_in, const int* in_sizes, int n_in,
                              void* d_out, int out_size, void* d_ws, size_t ws_size,
                              hipStream_t stream) {
    const float* x     = (const float*)d_in[0];
    const float* Wlow  = (const float*)d_in[1];
    const float* Wdt   = (const float*)d_in[2];
    const float* bias  = (const float*)d_in[3];
    const float* WB    = (const float*)d_in[4];
    const float* WC    = (const float*)d_in[5];
    const float* Alog  = (const float*)d_in[6];
    const float* Dv    = (const float*)d_in[7];
    float* out = (float*)d_out;
    float* wsf = (float*)d_ws;

    const size_t NCEN = (size_t)NC * EE * NS;   // 1,310,720 floats per carry array

    float* Bb = wsf;                   // [512][16]
    float* Cb = wsf + LL * NS;         // [512][16]
    float* X  = wsf + 2 * LL * NS;     // shared region
    float* part = X;                   // [8][512][192]   (G phase)
    float* tmp  = X + (size_t)KS * LL * NTOT;  // [512][160] (G phase)
    float* Pc     = X;                 // [NC][E][NS]     (scan phase, aliases part/tmp)
    float* Hloc   = X + NCEN;
    float* Hstart = X + 2 * NCEN;

    const size_t need_bytes = (2 * LL * NS + 3 * NCEN) * sizeof(float);

    g1_kernel<<<dim3(16, 3, 8), 256, 0, stream>>>(x, Wlow, WB, WC, part);
    r1_kernel<<<dim3(384), 256, 0, stream>>>(part, tmp, Bb, Cb);
    g2_kernel<<<dim3(16, 80), 256, 0, stream>>>(tmp, Wdt, bias, out);

    if (ws_size >= need_bytes) {
        passA_kernel<<<dim3(EE / 256, NC), 256, 0, stream>>>(out, x, Bb, Alog, Pc, Hloc);
        passB_kernel<<<dim3((EE * NS) / 256), 256, 0, stream>>>(Pc, Hloc, Hstart);
        passC_kernel<<<dim3(EE / 256, NC), 256, 0, stream>>>(x, Bb, Cb, Alog, Dv, Hstart, out);
    } else {
        scan_kernel<<<dim3(320), 256, 0, stream>>>(x, Bb, Cb, Alog, Dv, out);
    }
}

// Round 3
// 92.012 us; speedup vs baseline: 2.0794x; 1.3623x over previous
//
#include <hip/hip_runtime.h>
#include <math.h>

#define LL 512
#define EE 5120
#define RR 160
#define NS 16
#define NTOT 192   // 160 + 16 + 16
#define KS 16      // split-K for g1m
#define CH 32      // timesteps per chunk
#define NC 16      // number of chunks (LL/CH)

#define XCONV_BLOCKS 1280  // 512*5120 / 2048
#define WALL_TILES   960   // (5120/32)*(192/32)
#define WDT_TILES    800   // (5120/32)*(160/32)

typedef __attribute__((ext_vector_type(8))) short short8;
typedef __attribute__((ext_vector_type(4))) short short4v;
typedef __attribute__((ext_vector_type(4))) float f32x4;

__device__ inline float softplus_t(float z) {
    return z > 20.f ? z : log1pf(__expf(fminf(z, 20.f)));
}

__device__ inline short f2bf(float f) {
    unsigned u = __float_as_uint(f);
    unsigned r = (u + 0x7FFFu + ((u >> 16) & 1u)) >> 16;   // RNE
    return (short)r;
}

// ---- prep: x -> bf16 (row-major), [Wlow|WB|WC] -> WallT[192][5120] bf16,
//            Wdt -> WdtT[5120][160] bf16
__global__ __launch_bounds__(256) void prep_kernel(
        const float* __restrict__ x,
        const float* __restrict__ Wlow,
        const float* __restrict__ WB,
        const float* __restrict__ WC,
        const float* __restrict__ Wdt,
        short* __restrict__ xb,
        short* __restrict__ WallT,
        short* __restrict__ WdtT) {
    const int tid = threadIdx.x;
    const int bid = blockIdx.x;
    if (bid < XCONV_BLOCKS) {
        size_t base = (size_t)bid * 2048 + (size_t)tid * 8;
        float4 v0 = *reinterpret_cast<const float4*>(x + base);
        float4 v1 = *reinterpret_cast<const float4*>(x + base + 4);
        short8 o;
        o[0] = f2bf(v0.x); o[1] = f2bf(v0.y); o[2] = f2bf(v0.z); o[3] = f2bf(v0.w);
        o[4] = f2bf(v1.x); o[5] = f2bf(v1.y); o[6] = f2bf(v1.z); o[7] = f2bf(v1.w);
        *reinterpret_cast<short8*>(xb + base) = o;
    } else if (bid < XCONV_BLOCKS + WALL_TILES) {
        const int t = bid - XCONV_BLOCKS;
        const int k0 = (t / 6) * 32, n0 = (t % 6) * 32;
        __shared__ float tile[32][33];
        const int row = tid >> 3, col4 = (tid & 7) * 4;
#pragma unroll
        for (int i = 0; i < 4; ++i) {
            int n = n0 + col4 + i, k = k0 + row;
            float v;
            if (n < RR)            v = Wlow[(size_t)k * RR + n];
            else if (n < RR + NS)  v = WB[(size_t)k * NS + (n - RR)];
            else                   v = WC[(size_t)k * NS + (n - RR - NS)];
            tile[row][col4 + i] = v;
        }
        __syncthreads();
        const int nr = tid >> 3, kc = (tid & 7) * 4;
        short4v o;
#pragma unroll
        for (int i = 0; i < 4; ++i) o[i] = f2bf(tile[kc + i][nr]);
        *reinterpret_cast<short4v*>(WallT + (size_t)(n0 + nr) * EE + k0 + kc) = o;
    } else {
        const int t = bid - XCONV_BLOCKS - WALL_TILES;
        const int n0 = (t / 5) * 32, k0 = (t % 5) * 32;
        __shared__ float tile[32][33];
        const int row = tid >> 3, col4 = (tid & 7) * 4;
#pragma unroll
        for (int i = 0; i < 4; ++i)
            tile[row][col4 + i] = Wdt[(size_t)(k0 + row) * EE + n0 + col4 + i];
        __syncthreads();
        const int nr = tid >> 3, kc = (tid & 7) * 4;
        short4v o;
#pragma unroll
        for (int i = 0; i < 4; ++i) o[i] = f2bf(tile[kc + i][nr]);
        *reinterpret_cast<short4v*>(WdtT + (size_t)(n0 + nr) * RR + k0 + kc) = o;
    }
}

// ---- g1m: part[kz][512][192] = xb[:, kz-chunk] @ WallT^T[kz-chunk, :]  (bf16 MFMA)
__global__ __launch_bounds__(256) void g1m_kernel(
        const short* __restrict__ xb,
        const short* __restrict__ WallT,
        float* __restrict__ part) {
    const int tid = threadIdx.x;
    const int w = tid >> 6, l = tid & 63;
    const int wm = w >> 1, wn = w & 1;
    const int m0 = blockIdx.x * 64 + wm * 32;
    const int n0 = blockIdx.y * 64 + wn * 32;
    const int kz = blockIdx.z;
    const int row16 = l & 15, koff = (l >> 4) * 8;
    f32x4 acc[2][2] = {};
    const short* aptr0 = xb + (size_t)(m0 + row16) * EE + kz * 320 + koff;
    const short* aptr1 = aptr0 + (size_t)16 * EE;
    const short* bptr0 = WallT + (size_t)(n0 + row16) * EE + kz * 320 + koff;
    const short* bptr1 = bptr0 + (size_t)16 * EE;
#pragma unroll
    for (int s = 0; s < 10; ++s) {
        short8 a0 = *reinterpret_cast<const short8*>(aptr0 + s * 32);
        short8 a1 = *reinterpret_cast<const short8*>(aptr1 + s * 32);
        short8 b0 = *reinterpret_cast<const short8*>(bptr0 + s * 32);
        short8 b1 = *reinterpret_cast<const short8*>(bptr1 + s * 32);
        acc[0][0] = __builtin_amdgcn_mfma_f32_16x16x32_bf16(a0, b0, acc[0][0], 0, 0, 0);
        acc[0][1] = __builtin_amdgcn_mfma_f32_16x16x32_bf16(a0, b1, acc[0][1], 0, 0, 0);
        acc[1][0] = __builtin_amdgcn_mfma_f32_16x16x32_bf16(a1, b0, acc[1][0], 0, 0, 0);
        acc[1][1] = __builtin_amdgcn_mfma_f32_16x16x32_bf16(a1, b1, acc[1][1], 0, 0, 0);
    }
    const int r0 = (l >> 4) * 4;
    const int c = l & 15;
#pragma unroll
    for (int i = 0; i < 2; ++i)
#pragma unroll
        for (int j = 0; j < 2; ++j) {
            size_t base = ((size_t)kz * LL + (m0 + i * 16 + r0)) * NTOT + (n0 + j * 16 + c);
            part[base]            = acc[i][j][0];
            part[base + NTOT]     = acc[i][j][1];
            part[base + 2 * NTOT] = acc[i][j][2];
            part[base + 3 * NTOT] = acc[i][j][3];
        }
}

// ---- r1: reduce split-K partials -> tmpb (bf16, for g2m A), Bb, Cb (fp32)
__global__ __launch_bounds__(256) void r1_kernel(
        const float* __restrict__ part,
        short* __restrict__ tmpb,
        float* __restrict__ Bb,
        float* __restrict__ Cb) {
    int idx = blockIdx.x * 256 + threadIdx.x; // 0..98303
    int m = idx / NTOT, j = idx % NTOT;
    float s = 0.f;
#pragma unroll
    for (int ks = 0; ks < KS; ++ks) s += part[(size_t)ks * LL * NTOT + idx];
    if (j < RR) tmpb[m * RR + j] = f2bf(s);
    else if (j < RR + NS) Bb[m * NS + (j - RR)] = s;
    else Cb[m * NS + (j - RR - NS)] = s;
}

// ---- g2m: delta = softplus(tmpb @ WdtT^T + bias) -> out (delta storage), bf16 MFMA
__global__ __launch_bounds__(256) void g2m_kernel(
        const short* __restrict__ tmpb,
        const short* __restrict__ WdtT,
        const float* __restrict__ bias,
        float* __restrict__ delta) {
    const int tid = threadIdx.x;
    const int w = tid >> 6, l = tid & 63;
    const int wm = w >> 1, wn = w & 1;
    const int m0 = blockIdx.x * 64 + wm * 32;
    const int n0 = blockIdx.y * 64 + wn * 32;
    const int row16 = l & 15, koff = (l >> 4) * 8;
    f32x4 acc[2][2] = {};
    const short* aptr0 = tmpb + (size_t)(m0 + row16) * RR + koff;
    const short* aptr1 = aptr0 + (size_t)16 * RR;
    const short* bptr0 = WdtT + (size_t)(n0 + row16) * RR + koff;
    const short* bptr1 = bptr0 + (size_t)16 * RR;
#pragma unroll
    for (int s = 0; s < 5; ++s) {
        short8 a0 = *reinterpret_cast<const short8*>(aptr0 + s * 32);
        short8 a1 = *reinterpret_cast<const short8*>(aptr1 + s * 32);
        short8 b0 = *reinterpret_cast<const short8*>(bptr0 + s * 32);
        short8 b1 = *reinterpret_cast<const short8*>(bptr1 + s * 32);
        acc[0][0] = __builtin_amdgcn_mfma_f32_16x16x32_bf16(a0, b0, acc[0][0], 0, 0, 0);
        acc[0][1] = __builtin_amdgcn_mfma_f32_16x16x32_bf16(a0, b1, acc[0][1], 0, 0, 0);
        acc[1][0] = __builtin_amdgcn_mfma_f32_16x16x32_bf16(a1, b0, acc[1][0], 0, 0, 0);
        acc[1][1] = __builtin_amdgcn_mfma_f32_16x16x32_bf16(a1, b1, acc[1][1], 0, 0, 0);
    }
    const int r0 = (l >> 4) * 4;
    const int c = l & 15;
#pragma unroll
    for (int i = 0; i < 2; ++i) {
        int m = m0 + i * 16 + r0;
#pragma unroll
        for (int j = 0; j < 2; ++j) {
            int n = n0 + j * 16 + c;
            float bv = bias[n];
#pragma unroll
            for (int r = 0; r < 4; ++r)
                delta[(size_t)(m + r) * EE + n] = softplus_t(acc[i][j][r] + bv);
        }
    }
}

// ---- chunked scan: Pass A — per-chunk local scan, thread per e, 16 n's in registers
__global__ __launch_bounds__(256) void passA_kernel(
        const float* __restrict__ delta,  // lives in d_out
        const float* __restrict__ x,
        const float* __restrict__ Bb,
        const float* __restrict__ A_log,
        float* __restrict__ Pc,
        float* __restrict__ Hloc) {
    __shared__ float b_lds[CH][NS];
    const int c = blockIdx.y;
    const int e = blockIdx.x * 256 + threadIdx.x;
    const int t0 = c * CH;
    for (int v = threadIdx.x; v < CH * NS; v += 256)
        b_lds[v >> 4][v & 15] = Bb[t0 * NS + v];
    __syncthreads();

    float Ac[NS];
#pragma unroll
    for (int q = 0; q < 4; ++q) {
        float4 al = *reinterpret_cast<const float4*>(&A_log[(size_t)e * NS + q * 4]);
        Ac[q * 4 + 0] = -__expf(al.x);
        Ac[q * 4 + 1] = -__expf(al.y);
        Ac[q * 4 + 2] = -__expf(al.z);
        Ac[q * 4 + 3] = -__expf(al.w);
    }
    float h[NS];
#pragma unroll
    for (int n = 0; n < NS; ++n) h[n] = 0.f;
    float sumd = 0.f;

#pragma unroll 4
    for (int tt = 0; tt < CH; ++tt) {
        float d  = delta[(size_t)(t0 + tt) * EE + e];
        float xv = x[(size_t)(t0 + tt) * EE + e];
        sumd += d;
        float bx = d * xv;
#pragma unroll
        for (int n = 0; n < NS; ++n) {
            float a = __expf(d * Ac[n]);
            h[n] = a * h[n] + bx * b_lds[tt][n];
        }
    }
    size_t base = ((size_t)c * EE + e) * NS;
#pragma unroll
    for (int q = 0; q < 4; ++q) {
        float4 hv = {h[q*4], h[q*4+1], h[q*4+2], h[q*4+3]};
        *reinterpret_cast<float4*>(&Hloc[base + q * 4]) = hv;
        float4 pv;
        pv.x = __expf(Ac[q*4+0] * sumd);
        pv.y = __expf(Ac[q*4+1] * sumd);
        pv.z = __expf(Ac[q*4+2] * sumd);
        pv.w = __expf(Ac[q*4+3] * sumd);
        *reinterpret_cast<float4*>(&Pc[base + q * 4]) = pv;
    }
}

// Pass B — sequential combine over chunks, emits per-chunk starting state
__global__ __launch_bounds__(256) void passB_kernel(
        const float* __restrict__ Pc,
        const float* __restrict__ Hloc,
        float* __restrict__ Hstart) {
    const size_t idx = (size_t)blockIdx.x * 256 + threadIdx.x; // (e,n) flat
    float h = 0.f;
#pragma unroll
    for (int c = 0; c < NC; ++c) {
        size_t off = (size_t)c * EE * NS + idx;
        Hstart[off] = h;
        h = Pc[off] * h + Hloc[off];
    }
}

// Pass C — re-run chunk scans seeded with Hstart, in-register y reduction, fused skip
__global__ __launch_bounds__(256) void passC_kernel(
        const float* __restrict__ x,
        const float* __restrict__ Bb,
        const float* __restrict__ Cb,
        const float* __restrict__ A_log,
        const float* __restrict__ Dvec,
        const float* __restrict__ Hstart,
        float* __restrict__ out) {   // delta on entry, final output on exit
    __shared__ float b_lds[CH][NS];
    __shared__ float c_lds[CH][NS];
    const int c = blockIdx.y;
    const int e = blockIdx.x * 256 + threadIdx.x;
    const int t0 = c * CH;
    for (int v = threadIdx.x; v < CH * NS; v += 256) {
        b_lds[v >> 4][v & 15] = Bb[t0 * NS + v];
        c_lds[v >> 4][v & 15] = Cb[t0 * NS + v];
    }
    __syncthreads();

    float Ac[NS];
#pragma unroll
    for (int q = 0; q < 4; ++q) {
        float4 al = *reinterpret_cast<const float4*>(&A_log[(size_t)e * NS + q * 4]);
        Ac[q * 4 + 0] = -__expf(al.x);
        Ac[q * 4 + 1] = -__expf(al.y);
        Ac[q * 4 + 2] = -__expf(al.z);
        Ac[q * 4 + 3] = -__expf(al.w);
    }
    float h[NS];
    size_t hbase = ((size_t)c * EE + e) * NS;
#pragma unroll
    for (int q = 0; q < 4; ++q) {
        float4 hv = *reinterpret_cast<const float4*>(&Hstart[hbase + q * 4]);
        h[q*4+0] = hv.x; h[q*4+1] = hv.y; h[q*4+2] = hv.z; h[q*4+3] = hv.w;
    }
    const float Dval = Dvec[e];

#pragma unroll 4
    for (int tt = 0; tt < CH; ++tt) {
        float d  = out[(size_t)(t0 + tt) * EE + e];   // delta
        float xv = x[(size_t)(t0 + tt) * EE + e];
        float bx = d * xv;
        float y = 0.f;
#pragma unroll
        for (int n = 0; n < NS; ++n) {
            float a = __expf(d * Ac[n]);
            h[n] = a * h[n] + bx * b_lds[tt][n];
            y += h[n] * c_lds[tt][n];
        }
        out[(size_t)(t0 + tt) * EE + e] = xv * Dval + y;
    }
}

extern "C" void kernel_launch(void* const* d_in, const int* in_sizes, int n_in,
                              void* d_out, int out_size, void* d_ws, size_t ws_size,
                              hipStream_t stream) {
    const float* x     = (const float*)d_in[0];
    const float* Wlow  = (const float*)d_in[1];
    const float* Wdt   = (const float*)d_in[2];
    const float* bias  = (const float*)d_in[3];
    const float* WB    = (const float*)d_in[4];
    const float* WC    = (const float*)d_in[5];
    const float* Alog  = (const float*)d_in[6];
    const float* Dv    = (const float*)d_in[7];
    float* out = (float*)d_out;
    float* wsf = (float*)d_ws;

    float* Bb = wsf;                   // [512][16]
    float* Cb = wsf + LL * NS;         // [512][16]
    float* X  = wsf + 2 * LL * NS;     // shared region (3,932,160 floats)

    // GEMM-phase layout (all dead before the scan-phase aliases are written)
    short* xb    = (short*)X;                                   // 512*5120 bf16
    short* WallT = (short*)(X + 1310720);                       // 192*5120 bf16
    short* WdtT  = (short*)(X + 1310720 + 491520);              // 5120*160 bf16
    short* tmpb  = (short*)(X + 1310720 + 491520 + 409600);     // 512*160 bf16
    float* part  = X + 1310720 + 491520 + 409600 + 40960;       // 16*512*192 f32

    // scan-phase layout
    const size_t NCEN = (size_t)NC * EE * NS;  // 1,310,720
    float* Pc     = X;
    float* Hloc   = X + NCEN;
    float* Hstart = X + 2 * NCEN;

    prep_kernel<<<dim3(XCONV_BLOCKS + WALL_TILES + WDT_TILES), 256, 0, stream>>>(
        x, Wlow, WB, WC, Wdt, xb, WallT, WdtT);
    g1m_kernel<<<dim3(8, 3, KS), 256, 0, stream>>>(xb, WallT, part);
    r1_kernel<<<dim3(384), 256, 0, stream>>>(part, tmpb, Bb, Cb);
    g2m_kernel<<<dim3(8, 80), 256, 0, stream>>>(tmpb, WdtT, bias, out);
    passA_kernel<<<dim3(EE / 256, NC), 256, 0, stream>>>(out, x, Bb, Alog, Pc, Hloc);
    passB_kernel<<<dim3((EE * NS) / 256), 256, 0, stream>>>(Pc, Hloc, Hstart);
    passC_kernel<<<dim3(EE / 256, NC), 256, 0, stream>>>(x, Bb, Cb, Alog, Dv, Hstart, out);
}

// Round 5
// 74.446 us; speedup vs baseline: 2.5700x; 1.2359x over previous
//
#include <hip/hip_runtime.h>
#include <math.h>

#define LL 512
#define EE 5120
#define RR 160
#define NS 16
#define NTOT 192   // 160 + 16 + 16
#define KS 16      // split-K for g1m
#define CH 16      // timesteps per chunk
#define NC 32      // number of chunks (LL/CH)

#define WALL_TILES   960   // (5120/32)*(192/32)
#define WDT_TILES    800   // (5120/32)*(160/32)

typedef __attribute__((ext_vector_type(8))) short short8;
typedef __attribute__((ext_vector_type(4))) short short4v;
typedef __attribute__((ext_vector_type(4))) float f32x4;

__device__ inline float softplus_t(float z) {
    return z > 20.f ? z : log1pf(__expf(fminf(z, 20.f)));
}

__device__ inline short f2bf(float f) {
    unsigned u = __float_as_uint(f);
    unsigned r = (u + 0x7FFFu + ((u >> 16) & 1u)) >> 16;   // RNE
    return (short)r;
}

__device__ inline float bf2f(unsigned short u) {
    return __uint_as_float(((unsigned)u) << 16);
}

__device__ inline short8 cvt8(float4 a, float4 b) {
    short8 o;
    o[0] = f2bf(a.x); o[1] = f2bf(a.y); o[2] = f2bf(a.z); o[3] = f2bf(a.w);
    o[4] = f2bf(b.x); o[5] = f2bf(b.y); o[6] = f2bf(b.z); o[7] = f2bf(b.w);
    return o;
}

// ---- prepW: [Wlow|WB|WC] -> WallT[192][5120] bf16 ; Wdt -> WdtT[5120][160] bf16
__global__ __launch_bounds__(256) void prepW_kernel(
        const float* __restrict__ Wlow,
        const float* __restrict__ WB,
        const float* __restrict__ WC,
        const float* __restrict__ Wdt,
        short* __restrict__ WallT,
        short* __restrict__ WdtT) {
    const int tid = threadIdx.x;
    const int bid = blockIdx.x;
    __shared__ float tile[32][33];
    const int row = tid >> 3, col4 = (tid & 7) * 4;
    if (bid < WALL_TILES) {
        const int k0 = (bid / 6) * 32, n0 = (bid % 6) * 32;
#pragma unroll
        for (int i = 0; i < 4; ++i) {
            int n = n0 + col4 + i, k = k0 + row;
            float v;
            if (n < RR)            v = Wlow[(size_t)k * RR + n];
            else if (n < RR + NS)  v = WB[(size_t)k * NS + (n - RR)];
            else                   v = WC[(size_t)k * NS + (n - RR - NS)];
            tile[row][col4 + i] = v;
        }
        __syncthreads();
        const int nr = tid >> 3, kc = (tid & 7) * 4;
        short4v o;
#pragma unroll
        for (int i = 0; i < 4; ++i) o[i] = f2bf(tile[kc + i][nr]);
        *reinterpret_cast<short4v*>(WallT + (size_t)(n0 + nr) * EE + k0 + kc) = o;
    } else {
        const int t = bid - WALL_TILES;
        const int n0 = (t / 5) * 32, k0 = (t % 5) * 32;
#pragma unroll
        for (int i = 0; i < 4; ++i)
            tile[row][col4 + i] = Wdt[(size_t)(k0 + row) * EE + n0 + col4 + i];
        __syncthreads();
        const int nr = tid >> 3, kc = (tid & 7) * 4;
        short4v o;
#pragma unroll
        for (int i = 0; i < 4; ++i) o[i] = f2bf(tile[kc + i][nr]);
        *reinterpret_cast<short4v*>(WdtT + (size_t)(n0 + nr) * RR + k0 + kc) = o;
    }
}

// ---- g1m: part[kz][512][192] = x(fp32->bf16 inline)[:, kz-chunk] @ WallT^T (bf16 MFMA)
__global__ __launch_bounds__(256) void g1m_kernel(
        const float* __restrict__ x,
        const short* __restrict__ WallT,
        float* __restrict__ part) {
    const int tid = threadIdx.x;
    const int w = tid >> 6, l = tid & 63;
    const int wm = w >> 1, wn = w & 1;
    const int m0 = blockIdx.x * 64 + wm * 32;
    const int n0 = blockIdx.y * 64 + wn * 32;
    const int kz = blockIdx.z;
    const int row16 = l & 15, kg = (l >> 4) * 8;
    f32x4 acc[2][2] = {};
    const float* ap0 = x + (size_t)(m0 + row16) * EE + kz * 320 + kg;
    const float* ap1 = ap0 + (size_t)16 * EE;
    const short* bp0 = WallT + (size_t)(n0 + row16) * EE + kz * 320 + kg;
    const short* bp1 = bp0 + (size_t)16 * EE;
#pragma unroll
    for (int s = 0; s < 10; ++s) {
        short8 a0 = cvt8(*reinterpret_cast<const float4*>(ap0 + s * 32),
                         *reinterpret_cast<const float4*>(ap0 + s * 32 + 4));
        short8 a1 = cvt8(*reinterpret_cast<const float4*>(ap1 + s * 32),
                         *reinterpret_cast<const float4*>(ap1 + s * 32 + 4));
        short8 b0 = *reinterpret_cast<const short8*>(bp0 + s * 32);
        short8 b1 = *reinterpret_cast<const short8*>(bp1 + s * 32);
        acc[0][0] = __builtin_amdgcn_mfma_f32_16x16x32_bf16(a0, b0, acc[0][0], 0, 0, 0);
        acc[0][1] = __builtin_amdgcn_mfma_f32_16x16x32_bf16(a0, b1, acc[0][1], 0, 0, 0);
        acc[1][0] = __builtin_amdgcn_mfma_f32_16x16x32_bf16(a1, b0, acc[1][0], 0, 0, 0);
        acc[1][1] = __builtin_amdgcn_mfma_f32_16x16x32_bf16(a1, b1, acc[1][1], 0, 0, 0);
    }
    const int r0 = (l >> 4) * 4;
    const int c = l & 15;
#pragma unroll
    for (int i = 0; i < 2; ++i)
#pragma unroll
        for (int j = 0; j < 2; ++j) {
            size_t base = ((size_t)kz * LL + (m0 + i * 16 + r0)) * NTOT + (n0 + j * 16 + c);
            part[base]            = acc[i][j][0];
            part[base + NTOT]     = acc[i][j][1];
            part[base + 2 * NTOT] = acc[i][j][2];
            part[base + 3 * NTOT] = acc[i][j][3];
        }
}

// ---- r1: reduce split-K partials -> tmpb (bf16), Bb, Cb (fp32)
__global__ __launch_bounds__(256) void r1_kernel(
        const float* __restrict__ part,
        short* __restrict__ tmpb,
        float* __restrict__ Bb,
        float* __restrict__ Cb) {
    int idx = blockIdx.x * 256 + threadIdx.x; // 0..98303
    int m = idx / NTOT, j = idx % NTOT;
    float s = 0.f;
#pragma unroll
    for (int ks = 0; ks < KS; ++ks) s += part[(size_t)ks * LL * NTOT + idx];
    if (j < RR) tmpb[m * RR + j] = f2bf(s);
    else if (j < RR + NS) Bb[m * NS + (j - RR)] = s;
    else Cb[m * NS + (j - RR - NS)] = s;
}

// ---- g2m: deltab = softplus(tmpb @ WdtT^T + bias) -> bf16 in ws
__global__ __launch_bounds__(256) void g2m_kernel(
        const short* __restrict__ tmpb,
        const short* __restrict__ WdtT,
        const float* __restrict__ bias,
        unsigned short* __restrict__ deltab) {
    const int tid = threadIdx.x;
    const int w = tid >> 6, l = tid & 63;
    const int wm = w >> 1, wn = w & 1;
    const int m0 = blockIdx.x * 64 + wm * 32;
    const int n0 = blockIdx.y * 64 + wn * 32;
    const int row16 = l & 15, koff = (l >> 4) * 8;
    f32x4 acc[2][2] = {};
    const short* aptr0 = tmpb + (size_t)(m0 + row16) * RR + koff;
    const short* aptr1 = aptr0 + (size_t)16 * RR;
    const short* bptr0 = WdtT + (size_t)(n0 + row16) * RR + koff;
    const short* bptr1 = bptr0 + (size_t)16 * RR;
#pragma unroll
    for (int s = 0; s < 5; ++s) {
        short8 a0 = *reinterpret_cast<const short8*>(aptr0 + s * 32);
        short8 a1 = *reinterpret_cast<const short8*>(aptr1 + s * 32);
        short8 b0 = *reinterpret_cast<const short8*>(bptr0 + s * 32);
        short8 b1 = *reinterpret_cast<const short8*>(bptr1 + s * 32);
        acc[0][0] = __builtin_amdgcn_mfma_f32_16x16x32_bf16(a0, b0, acc[0][0], 0, 0, 0);
        acc[0][1] = __builtin_amdgcn_mfma_f32_16x16x32_bf16(a0, b1, acc[0][1], 0, 0, 0);
        acc[1][0] = __builtin_amdgcn_mfma_f32_16x16x32_bf16(a1, b0, acc[1][0], 0, 0, 0);
        acc[1][1] = __builtin_amdgcn_mfma_f32_16x16x32_bf16(a1, b1, acc[1][1], 0, 0, 0);
    }
    const int r0 = (l >> 4) * 4;
    const int c = l & 15;
#pragma unroll
    for (int i = 0; i < 2; ++i) {
        int m = m0 + i * 16 + r0;
#pragma unroll
        for (int j = 0; j < 2; ++j) {
            int n = n0 + j * 16 + c;
            float bv = bias[n];
#pragma unroll
            for (int r = 0; r < 4; ++r)
                deltab[(size_t)(m + r) * EE + n] =
                    (unsigned short)f2bf(softplus_t(acc[i][j][r] + bv));
        }
    }
}

// ---- passA: per-chunk local scan, thread per e, 16 n's in registers.
// Emits Hloc (bf16) and sumd (f32). Pc is recomputed in passB from sumd.
__global__ __launch_bounds__(256) void passA_kernel(
        const unsigned short* __restrict__ deltab,
        const float* __restrict__ x,
        const float* __restrict__ Bb,
        const float* __restrict__ A_log,
        unsigned short* __restrict__ Hloc,
        float* __restrict__ sumd) {
    __shared__ float b_lds[CH][NS];
    const int c = blockIdx.y;
    const int e = blockIdx.x * 256 + threadIdx.x;
    const int t0 = c * CH;
    for (int v = threadIdx.x; v < CH * NS; v += 256)
        b_lds[v >> 4][v & 15] = Bb[t0 * NS + v];
    __syncthreads();

    float Ac[NS];
#pragma unroll
    for (int q = 0; q < 4; ++q) {
        float4 al = *reinterpret_cast<const float4*>(&A_log[(size_t)e * NS + q * 4]);
        Ac[q * 4 + 0] = -__expf(al.x);
        Ac[q * 4 + 1] = -__expf(al.y);
        Ac[q * 4 + 2] = -__expf(al.z);
        Ac[q * 4 + 3] = -__expf(al.w);
    }
    float h[NS];
#pragma unroll
    for (int n = 0; n < NS; ++n) h[n] = 0.f;
    float sd = 0.f;

#pragma unroll
    for (int tt = 0; tt < CH; ++tt) {
        float d  = bf2f(deltab[(size_t)(t0 + tt) * EE + e]);
        float xv = x[(size_t)(t0 + tt) * EE + e];
        sd += d;
        float bx = d * xv;
#pragma unroll
        for (int n = 0; n < NS; ++n) {
            float a = __expf(d * Ac[n]);
            h[n] = a * h[n] + bx * b_lds[tt][n];
        }
    }
    size_t base = ((size_t)c * EE + e) * NS;
    short8 p0, p1;
#pragma unroll
    for (int n = 0; n < 8; ++n) { p0[n] = f2bf(h[n]); p1[n] = f2bf(h[n + 8]); }
    *reinterpret_cast<short8*>(Hloc + base)     = p0;
    *reinterpret_cast<short8*>(Hloc + base + 8) = p1;
    sumd[(size_t)c * EE + e] = sd;
}

// ---- passB: combine across chunks per (e,n); Pc = exp(A * sumd_c) recomputed
__global__ __launch_bounds__(256) void passB_kernel(
        const unsigned short* __restrict__ Hloc,
        const float* __restrict__ sumd,
        const float* __restrict__ A_log,
        unsigned short* __restrict__ Hstart) {
    const int wk = blockIdx.x * 256 + threadIdx.x;  // (e,n) flat, < 81920
    const int eB = wk >> 4;
    const float AcB = -__expf(A_log[wk]);
    float hs = 0.f;
#pragma unroll
    for (int cc = 0; cc < NC; ++cc) {
        size_t off = (size_t)cc * EE * NS + wk;
        Hstart[off] = (unsigned short)f2bf(hs);
        hs = __expf(AcB * sumd[(size_t)cc * EE + eB]) * hs + bf2f(Hloc[off]);
    }
}

// ---- passC: re-run chunk seeded with Hstart, in-register y reduction, fused skip
__global__ __launch_bounds__(256) void passC_kernel(
        const unsigned short* __restrict__ deltab,
        const float* __restrict__ x,
        const float* __restrict__ Bb,
        const float* __restrict__ Cb,
        const float* __restrict__ A_log,
        const float* __restrict__ Dvec,
        const unsigned short* __restrict__ Hstart,
        float* __restrict__ out) {
    __shared__ float b_lds[CH][NS];
    __shared__ float c_lds[CH][NS];
    const int c = blockIdx.y;
    const int e = blockIdx.x * 256 + threadIdx.x;
    const int t0 = c * CH;
    for (int v = threadIdx.x; v < CH * NS; v += 256) {
        b_lds[v >> 4][v & 15] = Bb[t0 * NS + v];
        c_lds[v >> 4][v & 15] = Cb[t0 * NS + v];
    }
    __syncthreads();

    float Ac[NS];
#pragma unroll
    for (int q = 0; q < 4; ++q) {
        float4 al = *reinterpret_cast<const float4*>(&A_log[(size_t)e * NS + q * 4]);
        Ac[q * 4 + 0] = -__expf(al.x);
        Ac[q * 4 + 1] = -__expf(al.y);
        Ac[q * 4 + 2] = -__expf(al.z);
        Ac[q * 4 + 3] = -__expf(al.w);
    }
    float h[NS];
    size_t base = ((size_t)c * EE + e) * NS;
    {
        short8 p0 = *reinterpret_cast<const short8*>(Hstart + base);
        short8 p1 = *reinterpret_cast<const short8*>(Hstart + base + 8);
#pragma unroll
        for (int n = 0; n < 8; ++n) {
            h[n]     = bf2f((unsigned short)p0[n]);
            h[n + 8] = bf2f((unsigned short)p1[n]);
        }
    }
    const float Dval = Dvec[e];

#pragma unroll
    for (int tt = 0; tt < CH; ++tt) {
        float d  = bf2f(deltab[(size_t)(t0 + tt) * EE + e]);
        float xv = x[(size_t)(t0 + tt) * EE + e];
        float bx = d * xv;
        float y = 0.f;
#pragma unroll
        for (int n = 0; n < NS; ++n) {
            float a = __expf(d * Ac[n]);
            h[n] = a * h[n] + bx * b_lds[tt][n];
            y += h[n] * c_lds[tt][n];
        }
        out[(size_t)(t0 + tt) * EE + e] = xv * Dval + y;
    }
}

extern "C" void kernel_launch(void* const* d_in, const int* in_sizes, int n_in,
                              void* d_out, int out_size, void* d_ws, size_t ws_size,
                              hipStream_t stream) {
    const float* x     = (const float*)d_in[0];
    const float* Wlow  = (const float*)d_in[1];
    const float* Wdt   = (const float*)d_in[2];
    const float* bias  = (const float*)d_in[3];
    const float* WB    = (const float*)d_in[4];
    const float* WC    = (const float*)d_in[5];
    const float* Alog  = (const float*)d_in[6];
    const float* Dv    = (const float*)d_in[7];
    float* out = (float*)d_out;
    float* wsf = (float*)d_ws;

    // flat workspace layout (float offsets; all 16B-aligned). Total 26.5 MB.
    float*          Bb     = wsf;                              // 8192 f32
    float*          Cb     = wsf + 8192;                       // 8192 f32
    short*          WallT  = (short*)(wsf + 16384);            // 983040 bf16
    short*          WdtT   = (short*)(wsf + 507904);           // 819200 bf16
    short*          tmpb   = (short*)(wsf + 917504);           // 81920 bf16
    float*          part   = wsf + 958464;                     // 1572864 f32
    unsigned short* deltab = (unsigned short*)(wsf + 2531328); // 2621440 bf16
    unsigned short* Hloc   = (unsigned short*)(wsf + 3842048); // 2621440 bf16
    unsigned short* Hstart = (unsigned short*)(wsf + 5152768); // 2621440 bf16
    float*          sumd   = wsf + 6463488;                    // 163840 f32

    prepW_kernel<<<dim3(WALL_TILES + WDT_TILES), 256, 0, stream>>>(
        Wlow, WB, WC, Wdt, WallT, WdtT);
    g1m_kernel<<<dim3(8, 3, KS), 256, 0, stream>>>(x, WallT, part);
    r1_kernel<<<dim3(384), 256, 0, stream>>>(part, tmpb, Bb, Cb);
    g2m_kernel<<<dim3(8, 80), 256, 0, stream>>>(tmpb, WdtT, bias, deltab);
    passA_kernel<<<dim3(EE / 256, NC), 256, 0, stream>>>(deltab, x, Bb, Alog, Hloc, sumd);
    passB_kernel<<<dim3((EE * NS) / 256), 256, 0, stream>>>(Hloc, sumd, Alog, Hstart);
    passC_kernel<<<dim3(EE / 256, NC), 256, 0, stream>>>(
        deltab, x, Bb, Cb, Alog, Dv, Hstart, out);
}

// Round 6
// 70.820 us; speedup vs baseline: 2.7016x; 1.0512x over previous
//
#include <hip/hip_runtime.h>
#include <math.h>

#define LL 512
#define EE 5120
#define RR 160
#define NS 16
#define NTOT 192   // 160 + 16 + 16
#define KS 32      // split-K for g1m
#define KCHUNK 160 // 5120/KS
#define CH 16      // timesteps per chunk
#define NC 32      // number of chunks (LL/CH)

#define XCONV_BLOCKS 1280  // 512*5120 / 2048
#define WALL_TILES   960   // (5120/32)*(192/32)
#define WDT_TILES    800   // (5120/32)*(160/32)

typedef __attribute__((ext_vector_type(8))) short short8;
typedef __attribute__((ext_vector_type(4))) short short4v;
typedef __attribute__((ext_vector_type(4))) float f32x4;

__device__ inline float softplus_t(float z) {
    return z > 20.f ? z : log1pf(__expf(fminf(z, 20.f)));
}

__device__ inline short f2bf(float f) {
    unsigned u = __float_as_uint(f);
    unsigned r = (u + 0x7FFFu + ((u >> 16) & 1u)) >> 16;   // RNE
    return (short)r;
}

__device__ inline float bf2f(unsigned short u) {
    return __uint_as_float(((unsigned)u) << 16);
}

// ---- prep: x -> xb bf16; [Wlow|WB|WC] -> WallT[192][5120] bf16; Wdt -> WdtT[5120][160] bf16
__global__ __launch_bounds__(256) void prep_kernel(
        const float* __restrict__ x,
        const float* __restrict__ Wlow,
        const float* __restrict__ WB,
        const float* __restrict__ WC,
        const float* __restrict__ Wdt,
        short* __restrict__ xb,
        short* __restrict__ WallT,
        short* __restrict__ WdtT) {
    const int tid = threadIdx.x;
    const int bid = blockIdx.x;
    if (bid < XCONV_BLOCKS) {
        size_t base = (size_t)bid * 2048 + (size_t)tid * 8;
        float4 v0 = *reinterpret_cast<const float4*>(x + base);
        float4 v1 = *reinterpret_cast<const float4*>(x + base + 4);
        short8 o;
        o[0] = f2bf(v0.x); o[1] = f2bf(v0.y); o[2] = f2bf(v0.z); o[3] = f2bf(v0.w);
        o[4] = f2bf(v1.x); o[5] = f2bf(v1.y); o[6] = f2bf(v1.z); o[7] = f2bf(v1.w);
        *reinterpret_cast<short8*>(xb + base) = o;
        return;
    }
    __shared__ float tile[32][33];
    const int row = tid >> 3, col4 = (tid & 7) * 4;
    if (bid < XCONV_BLOCKS + WALL_TILES) {
        const int t = bid - XCONV_BLOCKS;
        const int k0 = (t / 6) * 32, n0 = (t % 6) * 32;
#pragma unroll
        for (int i = 0; i < 4; ++i) {
            int n = n0 + col4 + i, k = k0 + row;
            float v;
            if (n < RR)            v = Wlow[(size_t)k * RR + n];
            else if (n < RR + NS)  v = WB[(size_t)k * NS + (n - RR)];
            else                   v = WC[(size_t)k * NS + (n - RR - NS)];
            tile[row][col4 + i] = v;
        }
        __syncthreads();
        const int nr = tid >> 3, kc = (tid & 7) * 4;
        short4v o;
#pragma unroll
        for (int i = 0; i < 4; ++i) o[i] = f2bf(tile[kc + i][nr]);
        *reinterpret_cast<short4v*>(WallT + (size_t)(n0 + nr) * EE + k0 + kc) = o;
    } else {
        const int t = bid - XCONV_BLOCKS - WALL_TILES;
        const int n0 = (t / 5) * 32, k0 = (t % 5) * 32;
#pragma unroll
        for (int i = 0; i < 4; ++i)
            tile[row][col4 + i] = Wdt[(size_t)(k0 + row) * EE + n0 + col4 + i];
        __syncthreads();
        const int nr = tid >> 3, kc = (tid & 7) * 4;
        short4v o;
#pragma unroll
        for (int i = 0; i < 4; ++i) o[i] = f2bf(tile[kc + i][nr]);
        *reinterpret_cast<short4v*>(WdtT + (size_t)(n0 + nr) * RR + k0 + kc) = o;
    }
}

// ---- g1m: part[kz][512][192] = xb[:, kz-chunk] @ WallT^T  (bf16 MFMA, KS=32)
__global__ __launch_bounds__(256) void g1m_kernel(
        const short* __restrict__ xb,
        const short* __restrict__ WallT,
        float* __restrict__ part) {
    const int tid = threadIdx.x;
    const int w = tid >> 6, l = tid & 63;
    const int wm = w >> 1, wn = w & 1;
    const int m0 = blockIdx.x * 64 + wm * 32;
    const int n0 = blockIdx.y * 64 + wn * 32;
    const int kz = blockIdx.z;
    const int row16 = l & 15, kg = (l >> 4) * 8;
    f32x4 acc[2][2] = {};
    const short* ap0 = xb + (size_t)(m0 + row16) * EE + kz * KCHUNK + kg;
    const short* ap1 = ap0 + (size_t)16 * EE;
    const short* bp0 = WallT + (size_t)(n0 + row16) * EE + kz * KCHUNK + kg;
    const short* bp1 = bp0 + (size_t)16 * EE;
#pragma unroll
    for (int s = 0; s < KCHUNK / 32; ++s) {
        short8 a0 = *reinterpret_cast<const short8*>(ap0 + s * 32);
        short8 a1 = *reinterpret_cast<const short8*>(ap1 + s * 32);
        short8 b0 = *reinterpret_cast<const short8*>(bp0 + s * 32);
        short8 b1 = *reinterpret_cast<const short8*>(bp1 + s * 32);
        acc[0][0] = __builtin_amdgcn_mfma_f32_16x16x32_bf16(a0, b0, acc[0][0], 0, 0, 0);
        acc[0][1] = __builtin_amdgcn_mfma_f32_16x16x32_bf16(a0, b1, acc[0][1], 0, 0, 0);
        acc[1][0] = __builtin_amdgcn_mfma_f32_16x16x32_bf16(a1, b0, acc[1][0], 0, 0, 0);
        acc[1][1] = __builtin_amdgcn_mfma_f32_16x16x32_bf16(a1, b1, acc[1][1], 0, 0, 0);
    }
    const int r0 = (l >> 4) * 4;
    const int c = l & 15;
#pragma unroll
    for (int i = 0; i < 2; ++i)
#pragma unroll
        for (int j = 0; j < 2; ++j) {
            size_t base = ((size_t)kz * LL + (m0 + i * 16 + r0)) * NTOT + (n0 + j * 16 + c);
            part[base]            = acc[i][j][0];
            part[base + NTOT]     = acc[i][j][1];
            part[base + 2 * NTOT] = acc[i][j][2];
            part[base + 3 * NTOT] = acc[i][j][3];
        }
}

// ---- r1: reduce split-K partials -> tmpb (bf16), Bb, Cb (fp32)
__global__ __launch_bounds__(256) void r1_kernel(
        const float* __restrict__ part,
        short* __restrict__ tmpb,
        float* __restrict__ Bb,
        float* __restrict__ Cb) {
    int idx = blockIdx.x * 256 + threadIdx.x; // 0..98303
    int m = idx / NTOT, j = idx % NTOT;
    float s = 0.f;
#pragma unroll
    for (int ks = 0; ks < KS; ++ks) s += part[(size_t)ks * LL * NTOT + idx];
    if (j < RR) tmpb[m * RR + j] = f2bf(s);
    else if (j < RR + NS) Bb[m * NS + (j - RR)] = s;
    else Cb[m * NS + (j - RR - NS)] = s;
}

// ---- g2m: deltab = softplus(tmpb @ WdtT^T + bias) -> bf16 in ws
__global__ __launch_bounds__(256) void g2m_kernel(
        const short* __restrict__ tmpb,
        const short* __restrict__ WdtT,
        const float* __restrict__ bias,
        unsigned short* __restrict__ deltab) {
    const int tid = threadIdx.x;
    const int w = tid >> 6, l = tid & 63;
    const int wm = w >> 1, wn = w & 1;
    const int m0 = blockIdx.x * 64 + wm * 32;
    const int n0 = blockIdx.y * 64 + wn * 32;
    const int row16 = l & 15, koff = (l >> 4) * 8;
    f32x4 acc[2][2] = {};
    const short* aptr0 = tmpb + (size_t)(m0 + row16) * RR + koff;
    const short* aptr1 = aptr0 + (size_t)16 * RR;
    const short* bptr0 = WdtT + (size_t)(n0 + row16) * RR + koff;
    const short* bptr1 = bptr0 + (size_t)16 * RR;
#pragma unroll
    for (int s = 0; s < 5; ++s) {
        short8 a0 = *reinterpret_cast<const short8*>(aptr0 + s * 32);
        short8 a1 = *reinterpret_cast<const short8*>(aptr1 + s * 32);
        short8 b0 = *reinterpret_cast<const short8*>(bptr0 + s * 32);
        short8 b1 = *reinterpret_cast<const short8*>(bptr1 + s * 32);
        acc[0][0] = __builtin_amdgcn_mfma_f32_16x16x32_bf16(a0, b0, acc[0][0], 0, 0, 0);
        acc[0][1] = __builtin_amdgcn_mfma_f32_16x16x32_bf16(a0, b1, acc[0][1], 0, 0, 0);
        acc[1][0] = __builtin_amdgcn_mfma_f32_16x16x32_bf16(a1, b0, acc[1][0], 0, 0, 0);
        acc[1][1] = __builtin_amdgcn_mfma_f32_16x16x32_bf16(a1, b1, acc[1][1], 0, 0, 0);
    }
    const int r0 = (l >> 4) * 4;
    const int c = l & 15;
#pragma unroll
    for (int i = 0; i < 2; ++i) {
        int m = m0 + i * 16 + r0;
#pragma unroll
        for (int j = 0; j < 2; ++j) {
            int n = n0 + j * 16 + c;
            float bv = bias[n];
#pragma unroll
            for (int r = 0; r < 4; ++r)
                deltab[(size_t)(m + r) * EE + n] =
                    (unsigned short)f2bf(softplus_t(acc[i][j][r] + bv));
        }
    }
}

// ---- passA: per-chunk local scan, thread per e, 16 n's in registers.
__global__ __launch_bounds__(256) void passA_kernel(
        const unsigned short* __restrict__ deltab,
        const unsigned short* __restrict__ xb,
        const float* __restrict__ Bb,
        const float* __restrict__ A_log,
        unsigned short* __restrict__ Hloc,
        float* __restrict__ sumd) {
    __shared__ float b_lds[CH][NS];
    const int c = blockIdx.y;
    const int e = blockIdx.x * 256 + threadIdx.x;
    const int t0 = c * CH;
    for (int v = threadIdx.x; v < CH * NS; v += 256)
        b_lds[v >> 4][v & 15] = Bb[t0 * NS + v];
    __syncthreads();

    float Ac[NS];
#pragma unroll
    for (int q = 0; q < 4; ++q) {
        float4 al = *reinterpret_cast<const float4*>(&A_log[(size_t)e * NS + q * 4]);
        Ac[q * 4 + 0] = -__expf(al.x);
        Ac[q * 4 + 1] = -__expf(al.y);
        Ac[q * 4 + 2] = -__expf(al.z);
        Ac[q * 4 + 3] = -__expf(al.w);
    }
    float h[NS];
#pragma unroll
    for (int n = 0; n < NS; ++n) h[n] = 0.f;
    float sd = 0.f;

#pragma unroll
    for (int tt = 0; tt < CH; ++tt) {
        float d  = bf2f(deltab[(size_t)(t0 + tt) * EE + e]);
        float xv = bf2f(xb[(size_t)(t0 + tt) * EE + e]);
        sd += d;
        float bx = d * xv;
#pragma unroll
        for (int n = 0; n < NS; ++n) {
            float a = __expf(d * Ac[n]);
            h[n] = a * h[n] + bx * b_lds[tt][n];
        }
    }
    size_t base = ((size_t)c * EE + e) * NS;
    short8 p0, p1;
#pragma unroll
    for (int n = 0; n < 8; ++n) { p0[n] = f2bf(h[n]); p1[n] = f2bf(h[n + 8]); }
    *reinterpret_cast<short8*>(Hloc + base)     = p0;
    *reinterpret_cast<short8*>(Hloc + base + 8) = p1;
    sumd[(size_t)c * EE + e] = sd;
}

// ---- passB: combine across chunks per (e,n); Pc = exp(A * sumd_c) recomputed
__global__ __launch_bounds__(256) void passB_kernel(
        const unsigned short* __restrict__ Hloc,
        const float* __restrict__ sumd,
        const float* __restrict__ A_log,
        unsigned short* __restrict__ Hstart) {
    const int wk = blockIdx.x * 256 + threadIdx.x;  // (e,n) flat, < 81920
    const int eB = wk >> 4;
    const float AcB = -__expf(A_log[wk]);
    float hs = 0.f;
#pragma unroll
    for (int cc = 0; cc < NC; ++cc) {
        size_t off = (size_t)cc * EE * NS + wk;
        Hstart[off] = (unsigned short)f2bf(hs);
        hs = __expf(AcB * sumd[(size_t)cc * EE + eB]) * hs + bf2f(Hloc[off]);
    }
}

// ---- passC: re-run chunk seeded with Hstart, in-register y reduction, fused skip
__global__ __launch_bounds__(256) void passC_kernel(
        const unsigned short* __restrict__ deltab,
        const unsigned short* __restrict__ xb,
        const float* __restrict__ Bb,
        const float* __restrict__ Cb,
        const float* __restrict__ A_log,
        const float* __restrict__ Dvec,
        const unsigned short* __restrict__ Hstart,
        float* __restrict__ out) {
    __shared__ float b_lds[CH][NS];
    __shared__ float c_lds[CH][NS];
    const int c = blockIdx.y;
    const int e = blockIdx.x * 256 + threadIdx.x;
    const int t0 = c * CH;
    for (int v = threadIdx.x; v < CH * NS; v += 256) {
        b_lds[v >> 4][v & 15] = Bb[t0 * NS + v];
        c_lds[v >> 4][v & 15] = Cb[t0 * NS + v];
    }
    __syncthreads();

    float Ac[NS];
#pragma unroll
    for (int q = 0; q < 4; ++q) {
        float4 al = *reinterpret_cast<const float4*>(&A_log[(size_t)e * NS + q * 4]);
        Ac[q * 4 + 0] = -__expf(al.x);
        Ac[q * 4 + 1] = -__expf(al.y);
        Ac[q * 4 + 2] = -__expf(al.z);
        Ac[q * 4 + 3] = -__expf(al.w);
    }
    float h[NS];
    size_t base = ((size_t)c * EE + e) * NS;
    {
        short8 p0 = *reinterpret_cast<const short8*>(Hstart + base);
        short8 p1 = *reinterpret_cast<const short8*>(Hstart + base + 8);
#pragma unroll
        for (int n = 0; n < 8; ++n) {
            h[n]     = bf2f((unsigned short)p0[n]);
            h[n + 8] = bf2f((unsigned short)p1[n]);
        }
    }
    const float Dval = Dvec[e];

#pragma unroll
    for (int tt = 0; tt < CH; ++tt) {
        float d  = bf2f(deltab[(size_t)(t0 + tt) * EE + e]);
        float xv = bf2f(xb[(size_t)(t0 + tt) * EE + e]);
        float bx = d * xv;
        float y = 0.f;
#pragma unroll
        for (int n = 0; n < NS; ++n) {
            float a = __expf(d * Ac[n]);
            h[n] = a * h[n] + bx * b_lds[tt][n];
            y += h[n] * c_lds[tt][n];
        }
        out[(size_t)(t0 + tt) * EE + e] = xv * Dval + y;
    }
}

extern "C" void kernel_launch(void* const* d_in, const int* in_sizes, int n_in,
                              void* d_out, int out_size, void* d_ws, size_t ws_size,
                              hipStream_t stream) {
    const float* x     = (const float*)d_in[0];
    const float* Wlow  = (const float*)d_in[1];
    const float* Wdt   = (const float*)d_in[2];
    const float* bias  = (const float*)d_in[3];
    const float* WB    = (const float*)d_in[4];
    const float* WC    = (const float*)d_in[5];
    const float* Alog  = (const float*)d_in[6];
    const float* Dv    = (const float*)d_in[7];
    float* out = (float*)d_out;
    float* wsf = (float*)d_ws;

    // flat workspace layout (float offsets; all 16B-aligned). Total ~38 MB.
    float*          Bb     = wsf;                              // 8192 f32
    float*          Cb     = wsf + 8192;                       // 8192 f32
    short*          WallT  = (short*)(wsf + 16384);            // 983040 bf16
    short*          WdtT   = (short*)(wsf + 507904);           // 819200 bf16
    short*          tmpb   = (short*)(wsf + 917504);           // 81920 bf16
    short*          xb     = (short*)(wsf + 958464);           // 2621440 bf16
    float*          part   = wsf + 2269184;                    // 3145728 f32
    unsigned short* deltab = (unsigned short*)(wsf + 5414912); // 2621440 bf16
    unsigned short* Hloc   = (unsigned short*)(wsf + 6725632); // 2621440 bf16
    unsigned short* Hstart = (unsigned short*)(wsf + 8036352); // 2621440 bf16
    float*          sumd   = wsf + 9347072;                    // 163840 f32

    prep_kernel<<<dim3(XCONV_BLOCKS + WALL_TILES + WDT_TILES), 256, 0, stream>>>(
        x, Wlow, WB, WC, Wdt, xb, WallT, WdtT);
    g1m_kernel<<<dim3(8, 3, KS), 256, 0, stream>>>(xb, WallT, part);
    r1_kernel<<<dim3(384), 256, 0, stream>>>(part, tmpb, Bb, Cb);
    g2m_kernel<<<dim3(8, 80), 256, 0, stream>>>(tmpb, WdtT, bias, deltab);
    passA_kernel<<<dim3(EE / 256, NC), 256, 0, stream>>>(
        deltab, (const unsigned short*)xb, Bb, Alog, Hloc, sumd);
    passB_kernel<<<dim3((EE * NS) / 256), 256, 0, stream>>>(Hloc, sumd, Alog, Hstart);
    passC_kernel<<<dim3(EE / 256, NC), 256, 0, stream>>>(
        deltab, (const unsigned short*)xb, Bb, Cb, Alog, Dv, Hstart, out);
}